// Round 1
// baseline (1035.211 us; speedup 1.0000x reference)
//
#include <hip/hip_runtime.h>

typedef __bf16 bf16;
typedef __attribute__((ext_vector_type(8))) __bf16 bf16x8;
typedef __attribute__((ext_vector_type(4))) float f32x4;

#define MFMA(a, b, c) __builtin_amdgcn_mfma_f32_16x16x32_bf16(a, b, c, 0, 0, 0)

constexpr int T_ = 2048, B_ = 2, E_ = 1024, H_ = 16, HD = 64;
constexpr int BH = B_ * H_;          // 32
constexpr int M_ = T_ * B_;          // 4096 tokens
constexpr size_t SEC = (size_t)BH * T_ * HD;  // elems per q/k/v section

// convert 8 consecutive fp32 (memory) -> bf16x8
__device__ inline bf16x8 cvt8(const float* p) {
    const float4* q = (const float4*)p;
    float4 a = q[0], b = q[1];
    bf16x8 r;
    r[0] = (bf16)a.x; r[1] = (bf16)a.y; r[2] = (bf16)a.z; r[3] = (bf16)a.w;
    r[4] = (bf16)b.x; r[5] = (bf16)b.y; r[6] = (bf16)b.z; r[7] = (bf16)b.w;
    return r;
}
// convert 8 fp32 already in registers -> bf16x8
__device__ inline bf16x8 cvt8v(const float4& a, const float4& b) {
    bf16x8 r;
    r[0] = (bf16)a.x; r[1] = (bf16)a.y; r[2] = (bf16)a.z; r[3] = (bf16)a.w;
    r[4] = (bf16)b.x; r[5] = (bf16)b.y; r[6] = (bf16)b.z; r[7] = (bf16)b.w;
    return r;
}

// ---------------------------------------------------------------------------
// Kernel A: qkv = g @ W_in^T + b_in (fp32 in), q *= 0.125, bf16 out scattered
// to [bh][t][d]. M=4096, N=3072, K=1024. 128x128 tile, BK=32, 4 waves, each
// wave owns a 64x64 quadrant (4x4 of 16x16 frags). Raw-fp32 register
// prefetch; cvt to bf16 happens at LDS-write time (data long arrived).
// ---------------------------------------------------------------------------
__global__ __launch_bounds__(256) void qkv_gemm(const float* __restrict__ g,
                                                const float* __restrict__ Win,
                                                const float* __restrict__ bin,
                                                bf16* __restrict__ qkv) {
    __shared__ bf16 As[128][40];
    __shared__ bf16 Bs[128][40];
    const int tid = threadIdx.x;
    const int mbase = blockIdx.y * 128;
    const int nbase = blockIdx.x * 128;
    const int wave = tid >> 6, lane = tid & 63;
    const int quad = lane >> 4, l16 = lane & 15;
    const int wm = (wave >> 1) * 64, wn = (wave & 1) * 64;

    // staging: each thread owns 16 consecutive floats of one row per matrix
    const int srow = tid >> 1, scol = (tid & 1) * 16;
    const float* ga = g + (size_t)(mbase + srow) * E_ + scol;
    const float* gb = Win + (size_t)(nbase + srow) * E_ + scol;

    f32x4 acc[4][4] = {};
    float4 pa[4], pb_[4];
    pa[0] = *(const float4*)(ga + 0);  pa[1] = *(const float4*)(ga + 4);
    pa[2] = *(const float4*)(ga + 8);  pa[3] = *(const float4*)(ga + 12);
    pb_[0] = *(const float4*)(gb + 0); pb_[1] = *(const float4*)(gb + 4);
    pb_[2] = *(const float4*)(gb + 8); pb_[3] = *(const float4*)(gb + 12);

    for (int kk = 0; kk < E_; kk += 32) {
        __syncthreads();                      // prev iteration's reads done
        *(bf16x8*)&As[srow][scol]     = cvt8v(pa[0], pa[1]);
        *(bf16x8*)&As[srow][scol + 8] = cvt8v(pa[2], pa[3]);
        *(bf16x8*)&Bs[srow][scol]     = cvt8v(pb_[0], pb_[1]);
        *(bf16x8*)&Bs[srow][scol + 8] = cvt8v(pb_[2], pb_[3]);
        if (kk + 32 < E_) {                   // prefetch next tile (raw fp32)
            const float* a2 = ga + kk + 32;
            const float* b2 = gb + kk + 32;
            pa[0] = *(const float4*)(a2 + 0);  pa[1] = *(const float4*)(a2 + 4);
            pa[2] = *(const float4*)(a2 + 8);  pa[3] = *(const float4*)(a2 + 12);
            pb_[0] = *(const float4*)(b2 + 0); pb_[1] = *(const float4*)(b2 + 4);
            pb_[2] = *(const float4*)(b2 + 8); pb_[3] = *(const float4*)(b2 + 12);
        }
        __syncthreads();                      // tiles ready
        bf16x8 af[4], bfr[4];
        for (int i = 0; i < 4; i++)
            af[i] = *(const bf16x8*)&As[wm + i * 16 + l16][quad * 8];
        for (int j = 0; j < 4; j++)
            bfr[j] = *(const bf16x8*)&Bs[wn + j * 16 + l16][quad * 8];
        for (int i = 0; i < 4; i++)
            for (int j = 0; j < 4; j++)
                acc[i][j] = MFMA(af[i], bfr[j], acc[i][j]);
    }

    float bias[4];
    for (int j = 0; j < 4; j++) bias[j] = bin[nbase + wn + j * 16 + l16];
    for (int i = 0; i < 4; i++)
        for (int j = 0; j < 4; j++) {
            int gcol = nbase + wn + j * 16 + l16;            // 0..3071
            int which = gcol >> 10, e = gcol & 1023;
            int h = e >> 6, d = e & 63;
            float sc = (gcol < E_) ? 0.125f : 1.0f;          // q scaling
            for (int r = 0; r < 4; r++) {
                int grow = mbase + wm + i * 16 + quad * 4 + r;  // token
                int t = grow >> 1, b = grow & 1;
                float v = (acc[i][j][r] + bias[j]) * sc;
                qkv[(size_t)which * SEC + (size_t)(b * H_ + h) * T_ * HD +
                    (size_t)t * HD + d] = (bf16)v;
            }
        }
}

// ---------------------------------------------------------------------------
// Kernel B: single-pass attention with deferred normalization.
// Per (bh, 64-row q tile): for each K/V tile compute S, e=exp(S); accumulate
// row sums and O += e.V (unnormalized); store unnormalized e to p.
// Epilogue: O *= 1/rowsum; rescale p in place (each thread re-reads exactly
// the addresses it wrote -> same-thread visibility, reads mostly L2/L3).
// K/V staged via register prefetch (issue-early / write-late).
// ---------------------------------------------------------------------------
__global__ __launch_bounds__(256) void attn_kernel(bf16* __restrict__ qkv,
                                                   float* __restrict__ p_out) {
    __shared__ bf16 Qs[64][72];
    __shared__ bf16 Ks[64][72];
    __shared__ bf16 Vt[64][72];   // transposed V tile: [d][s]
    __shared__ float Ps[64][68];  // fp32 unnormalized exp tile
    __shared__ float rinv_s[64];

    const int tid = threadIdx.x;
    const int qt = blockIdx.x, bh = blockIdx.y;
    const int wave = tid >> 6, lane = tid & 63;
    const int quad = lane >> 4, l16 = lane & 15;

    bf16* qb = qkv + (size_t)bh * T_ * HD + (size_t)qt * 64 * HD;
    const bf16* kb = qkv + SEC + (size_t)bh * T_ * HD;
    const bf16* vb = qkv + 2 * SEC + (size_t)bh * T_ * HD;

    const int r0 = tid >> 3, c0 = (tid & 7) * 8;
    for (int rep = 0; rep < 2; rep++) {
        int r = r0 + rep * 32;
        *(uint4*)&Qs[r][c0] = *(const uint4*)(qb + (size_t)r * HD + c0);
    }
    // prefetch K/V tile 0 into registers
    uint4 kreg[2];
    bf16x8 vreg[2];
    for (int rep = 0; rep < 2; rep++) {
        int r = r0 + rep * 32;
        kreg[rep] = *(const uint4*)(kb + (size_t)r * HD + c0);
        vreg[rep] = *(const bf16x8*)(vb + (size_t)r * HD + c0);
    }
    __syncthreads();

    bf16x8 aq0 = *(const bf16x8*)&Qs[wave * 16 + l16][quad * 8];
    bf16x8 aq1 = *(const bf16x8*)&Qs[wave * 16 + l16][32 + quad * 8];

    float rs[4] = {0.f, 0.f, 0.f, 0.f};
    f32x4 oacc[4] = {};
    float* pb0 = p_out + (size_t)bh * T_ * T_ + (size_t)(qt * 64) * T_;

    for (int kt = 0; kt < 32; kt++) {
        __syncthreads();  // A: previous iteration's Ks/Vt/Ps reads done
        for (int rep = 0; rep < 2; rep++) {
            int r = r0 + rep * 32;
            *(uint4*)&Ks[r][c0] = kreg[rep];
            for (int j = 0; j < 8; j++) Vt[c0 + j][r] = vreg[rep][j];
        }
        if (kt + 1 < 32) {  // issue next tile's loads; consumed next iter
            for (int rep = 0; rep < 2; rep++) {
                int r = r0 + rep * 32;
                kreg[rep] = *(const uint4*)(kb + (size_t)((kt + 1) * 64 + r) * HD + c0);
                vreg[rep] = *(const bf16x8*)(vb + (size_t)((kt + 1) * 64 + r) * HD + c0);
            }
        }
        __syncthreads();  // B: tiles ready

        for (int jn = 0; jn < 4; jn++) {
            f32x4 s = {};
            bf16x8 b0 = *(const bf16x8*)&Ks[jn * 16 + l16][quad * 8];
            bf16x8 b1 = *(const bf16x8*)&Ks[jn * 16 + l16][32 + quad * 8];
            s = MFMA(aq0, b0, s);
            s = MFMA(aq1, b1, s);
            for (int r = 0; r < 4; r++) {
                float e = __expf(s[r]);
                rs[r] += e;
                Ps[wave * 16 + quad * 4 + r][jn * 16 + l16] = e;
            }
        }
        __syncthreads();  // C: Ps ready

        // unnormalized p store (coalesced from LDS; rescaled in epilogue)
        float* pb = pb0 + kt * 64;
        for (int rep = 0; rep < 4; rep++) {
            int idx = tid + rep * 256;
            int r = idx >> 4, c = (idx & 15) * 4;
            *(float4*)(pb + (size_t)r * T_ + c) = *(const float4*)&Ps[r][c];
        }
        // O += E x V^T (unnormalized)
        bf16x8 a0 = cvt8(&Ps[wave * 16 + l16][quad * 8]);
        bf16x8 a1 = cvt8(&Ps[wave * 16 + l16][32 + quad * 8]);
        for (int jb = 0; jb < 4; jb++) {
            bf16x8 b0 = *(const bf16x8*)&Vt[jb * 16 + l16][quad * 8];
            bf16x8 b1 = *(const bf16x8*)&Vt[jb * 16 + l16][32 + quad * 8];
            oacc[jb] = MFMA(a0, b0, oacc[jb]);
            oacc[jb] = MFMA(a1, b1, oacc[jb]);
        }
    }

    // row sums: reduce across the 16 lanes of each l16 group
    for (int off = 8; off; off >>= 1)
        for (int r = 0; r < 4; r++) rs[r] += __shfl_xor(rs[r], off, 16);
    if (l16 == 0)
        for (int r = 0; r < 4; r++)
            rinv_s[wave * 16 + quad * 4 + r] = 1.0f / rs[r];
    __syncthreads();  // also drains all p stores (vmcnt) before rescale

    float ri[4];
    for (int r = 0; r < 4; r++) ri[r] = rinv_s[wave * 16 + quad * 4 + r];

    // normalized O overwrites this block's own q tile
    for (int jb = 0; jb < 4; jb++)
        for (int r = 0; r < 4; r++)
            qb[(size_t)(wave * 16 + quad * 4 + r) * HD + jb * 16 + l16] =
                (bf16)(oacc[jb][r] * ri[r]);

    // in-place rescale of p: identical index formula as the store loop, so
    // each thread touches exactly its own prior writes (L2/L3-resident)
    float rw[4];
    for (int rep = 0; rep < 4; rep++) rw[rep] = rinv_s[(tid >> 4) + rep * 16];
    for (int kt = 0; kt < 32; kt++) {
        float* pb = pb0 + kt * 64;
        for (int rep = 0; rep < 4; rep++) {
            int idx = tid + rep * 256;
            int r = idx >> 4, c = (idx & 15) * 4;
            float4* ap = (float4*)(pb + (size_t)r * T_ + c);
            float4 x = *ap;
            x.x *= rw[rep]; x.y *= rw[rep]; x.z *= rw[rep]; x.w *= rw[rep];
            *ap = x;
        }
    }
}

// ---------------------------------------------------------------------------
// Kernel C: out = attn @ W_out^T + b_out (fp32 out). M=4096, N=1024, K=1024.
// A (bf16) gathered from head layout [bh][t][d] (= q section of ws).
// ---------------------------------------------------------------------------
__global__ __launch_bounds__(256) void out_gemm(const bf16* __restrict__ attn,
                                                const float* __restrict__ Wout,
                                                const float* __restrict__ bout,
                                                float* __restrict__ out) {
    __shared__ bf16 As[64][40];
    __shared__ bf16 Bs[64][40];
    const int tid = threadIdx.x;
    const int mbase = blockIdx.y * 64;
    const int nbase = blockIdx.x * 64;
    const int wave = tid >> 6, lane = tid & 63;
    const int quad = lane >> 4, l16 = lane & 15;
    const int wm = (wave >> 1) * 32, wn = (wave & 1) * 32;

    f32x4 acc[2][2] = {};
    const int lrow = tid >> 2, lcol = (tid & 3) * 8;
    const int arow = mbase + lrow;
    const int tok_t = arow >> 1, tok_b = arow & 1;
    const float* gb = Wout + (size_t)(nbase + lrow) * E_ + lcol;

    for (int kk = 0; kk < E_; kk += 32) {
        int kc = kk + lcol;
        int h = kc >> 6, d = kc & 63;
        *(uint4*)&As[lrow][lcol] = *(const uint4*)(attn +
            (size_t)(tok_b * H_ + h) * T_ * HD + (size_t)tok_t * HD + d);
        *(bf16x8*)&Bs[lrow][lcol] = cvt8(gb + kk);
        __syncthreads();
        bf16x8 a0 = *(const bf16x8*)&As[wm + l16][quad * 8];
        bf16x8 a1 = *(const bf16x8*)&As[wm + 16 + l16][quad * 8];
        bf16x8 b0 = *(const bf16x8*)&Bs[wn + l16][quad * 8];
        bf16x8 b1 = *(const bf16x8*)&Bs[wn + 16 + l16][quad * 8];
        acc[0][0] = MFMA(a0, b0, acc[0][0]);
        acc[0][1] = MFMA(a0, b1, acc[0][1]);
        acc[1][0] = MFMA(a1, b0, acc[1][0]);
        acc[1][1] = MFMA(a1, b1, acc[1][1]);
        __syncthreads();
    }
    for (int i = 0; i < 2; i++)
        for (int j = 0; j < 2; j++)
            for (int r = 0; r < 4; r++) {
                int grow = mbase + wm + i * 16 + quad * 4 + r;
                int gcol = nbase + wn + j * 16 + l16;
                out[(size_t)grow * E_ + gcol] = acc[i][j][r] + bout[gcol];
            }
}

extern "C" void kernel_launch(void* const* d_in, const int* in_sizes, int n_in,
                              void* d_out, int out_size, void* d_ws, size_t ws_size,
                              hipStream_t stream) {
    const float* g = (const float*)d_in[0];
    const float* Win = (const float*)d_in[1];
    const float* bin = (const float*)d_in[2];
    const float* Wout = (const float*)d_in[3];
    const float* bout = (const float*)d_in[4];

    float* out = (float*)d_out;               // 4,194,304 fp32
    float* p = out + (size_t)M_ * E_;         // 134,217,728 fp32
    bf16* qkv_ws = (bf16*)d_ws;               // 3 * SEC bf16 = 24 MB

    qkv_gemm<<<dim3(24, 32), 256, 0, stream>>>(g, Win, bin, qkv_ws);
    attn_kernel<<<dim3(32, 32), 256, 0, stream>>>(qkv_ws, p);
    out_gemm<<<dim3(16, 64), 256, 0, stream>>>(qkv_ws, Wout, bout, out);
}

// Round 2
// 1012.599 us; speedup vs baseline: 1.0223x; 1.0223x over previous
//
#include <hip/hip_runtime.h>

typedef __bf16 bf16;
typedef __attribute__((ext_vector_type(8))) __bf16 bf16x8;
typedef __attribute__((ext_vector_type(4))) float f32x4;

#define MFMA(a, b, c) __builtin_amdgcn_mfma_f32_16x16x32_bf16(a, b, c, 0, 0, 0)

constexpr int T_ = 2048, B_ = 2, E_ = 1024, H_ = 16, HD = 64;
constexpr int BH = B_ * H_;          // 32
constexpr int M_ = T_ * B_;          // 4096 tokens
constexpr size_t SEC = (size_t)BH * T_ * HD;  // elems per q/k/v section

// convert 8 consecutive fp32 (memory) -> bf16x8
__device__ inline bf16x8 cvt8(const float* p) {
    const float4* q = (const float4*)p;
    float4 a = q[0], b = q[1];
    bf16x8 r;
    r[0] = (bf16)a.x; r[1] = (bf16)a.y; r[2] = (bf16)a.z; r[3] = (bf16)a.w;
    r[4] = (bf16)b.x; r[5] = (bf16)b.y; r[6] = (bf16)b.z; r[7] = (bf16)b.w;
    return r;
}
// convert 8 fp32 already in registers -> bf16x8
__device__ inline bf16x8 cvt8v(const float4& a, const float4& b) {
    bf16x8 r;
    r[0] = (bf16)a.x; r[1] = (bf16)a.y; r[2] = (bf16)a.z; r[3] = (bf16)a.w;
    r[4] = (bf16)b.x; r[5] = (bf16)b.y; r[6] = (bf16)b.z; r[7] = (bf16)b.w;
    return r;
}

// ---------------------------------------------------------------------------
// Kernel A: qkv = g @ W_in^T + b_in (fp32 in), q *= 0.125, bf16 out scattered.
// q,k sections in [bh][t][d]; V section written TRANSPOSED as [bh][d][t] so
// the attention kernel can stage V^T tiles with coalesced vector loads
// (eliminates the 16-way-conflict LDS transpose that cost 5.3e7 conflict
// cycles in round 1). Scatter store count unchanged; only addresses differ.
// ---------------------------------------------------------------------------
__global__ __launch_bounds__(256) void qkv_gemm(const float* __restrict__ g,
                                                const float* __restrict__ Win,
                                                const float* __restrict__ bin,
                                                bf16* __restrict__ qkv) {
    __shared__ bf16 As[128][40];
    __shared__ bf16 Bs[128][40];
    const int tid = threadIdx.x;
    const int mbase = blockIdx.y * 128;
    const int nbase = blockIdx.x * 128;
    const int wave = tid >> 6, lane = tid & 63;
    const int quad = lane >> 4, l16 = lane & 15;
    const int wm = (wave >> 1) * 64, wn = (wave & 1) * 64;

    const int srow = tid >> 1, scol = (tid & 1) * 16;
    const float* ga = g + (size_t)(mbase + srow) * E_ + scol;
    const float* gb = Win + (size_t)(nbase + srow) * E_ + scol;

    f32x4 acc[4][4] = {};
    float4 pa[4], pb_[4];
    pa[0] = *(const float4*)(ga + 0);  pa[1] = *(const float4*)(ga + 4);
    pa[2] = *(const float4*)(ga + 8);  pa[3] = *(const float4*)(ga + 12);
    pb_[0] = *(const float4*)(gb + 0); pb_[1] = *(const float4*)(gb + 4);
    pb_[2] = *(const float4*)(gb + 8); pb_[3] = *(const float4*)(gb + 12);

    for (int kk = 0; kk < E_; kk += 32) {
        __syncthreads();
        *(bf16x8*)&As[srow][scol]     = cvt8v(pa[0], pa[1]);
        *(bf16x8*)&As[srow][scol + 8] = cvt8v(pa[2], pa[3]);
        *(bf16x8*)&Bs[srow][scol]     = cvt8v(pb_[0], pb_[1]);
        *(bf16x8*)&Bs[srow][scol + 8] = cvt8v(pb_[2], pb_[3]);
        if (kk + 32 < E_) {
            const float* a2 = ga + kk + 32;
            const float* b2 = gb + kk + 32;
            pa[0] = *(const float4*)(a2 + 0);  pa[1] = *(const float4*)(a2 + 4);
            pa[2] = *(const float4*)(a2 + 8);  pa[3] = *(const float4*)(a2 + 12);
            pb_[0] = *(const float4*)(b2 + 0); pb_[1] = *(const float4*)(b2 + 4);
            pb_[2] = *(const float4*)(b2 + 8); pb_[3] = *(const float4*)(b2 + 12);
        }
        __syncthreads();
        bf16x8 af[4], bfr[4];
        for (int i = 0; i < 4; i++)
            af[i] = *(const bf16x8*)&As[wm + i * 16 + l16][quad * 8];
        for (int j = 0; j < 4; j++)
            bfr[j] = *(const bf16x8*)&Bs[wn + j * 16 + l16][quad * 8];
        for (int i = 0; i < 4; i++)
            for (int j = 0; j < 4; j++)
                acc[i][j] = MFMA(af[i], bfr[j], acc[i][j]);
    }

    float bias[4];
    for (int j = 0; j < 4; j++) bias[j] = bin[nbase + wn + j * 16 + l16];
    for (int i = 0; i < 4; i++)
        for (int j = 0; j < 4; j++) {
            int gcol = nbase + wn + j * 16 + l16;            // 0..3071
            int which = gcol >> 10, e = gcol & 1023;         // uniform per j
            int h = e >> 6, d = e & 63;
            float sc = (gcol < E_) ? 0.125f : 1.0f;
            for (int r = 0; r < 4; r++) {
                int grow = mbase + wm + i * 16 + quad * 4 + r;
                int t = grow >> 1, b = grow & 1;
                float v = (acc[i][j][r] + bias[j]) * sc;
                size_t addr;
                if (which == 2)   // V^T: [bh][d][t]
                    addr = 2 * SEC + (size_t)(b * H_ + h) * HD * T_ +
                           (size_t)d * T_ + t;
                else              // q,k: [bh][t][d]
                    addr = (size_t)which * SEC + (size_t)(b * H_ + h) * T_ * HD +
                           (size_t)t * HD + d;
                qkv[addr] = (bf16)v;
            }
        }
}

// ---------------------------------------------------------------------------
// Kernel B: two-pass attention, p written ONCE (normalized).
// Pass 1: rowsums of exp(S) with K fragments loaded DIRECTLY from global
// (L2-resident; 16 fully-consumed 64B lines per load instr) — no LDS, no
// barriers. Butterfly-reduce gives every lane its row sums -> ri in regs.
// Pass 2: K and V^T staged via register prefetch -> LDS (all vector ops,
// conflict-free); S recomputed (bit-identical), e*ri stored direct to p from
// registers (64B segments) and to bf16 PsB (wave-local -> no barrier) for
// the PV A-fragment. 2 barriers/kt. O overwrites this block's q tile.
// ---------------------------------------------------------------------------
__global__ __launch_bounds__(256) void attn_kernel(bf16* __restrict__ qkv,
                                                   float* __restrict__ p_out) {
    __shared__ bf16 Ks[64][72];
    __shared__ bf16 Vts[64][72];   // V^T tile: [d][s]
    __shared__ bf16 PsB[64][72];   // normalized probs, bf16 (A-frag staging)

    const int tid = threadIdx.x;
    const int qt = blockIdx.x, bh = blockIdx.y;
    const int wave = tid >> 6, lane = tid & 63;
    const int quad = lane >> 4, l16 = lane & 15;

    bf16* qb = qkv + (size_t)bh * T_ * HD + (size_t)qt * 64 * HD;
    const bf16* kb = qkv + SEC + (size_t)bh * T_ * HD;        // [t][d]
    const bf16* vt = qkv + 2 * SEC + (size_t)bh * HD * T_;    // [d][t]

    // Q fragments direct from global (row stride 128B, 16B aligned)
    bf16x8 aq0 = *(const bf16x8*)(qb + (size_t)(wave * 16 + l16) * HD + quad * 8);
    bf16x8 aq1 = *(const bf16x8*)(qb + (size_t)(wave * 16 + l16) * HD + 32 + quad * 8);

    // ---- pass 1: row sums, no LDS, no barriers ----
    float rs[4] = {0.f, 0.f, 0.f, 0.f};
    for (int kt = 0; kt < 32; kt++) {
        const bf16* kbt = kb + (size_t)kt * 64 * HD;
        bf16x8 k0[4], k1[4];
#pragma unroll
        for (int jn = 0; jn < 4; jn++) {
            const bf16* p = kbt + (size_t)(jn * 16 + l16) * HD + quad * 8;
            k0[jn] = *(const bf16x8*)p;
            k1[jn] = *(const bf16x8*)(p + 32);
        }
#pragma unroll
        for (int jn = 0; jn < 4; jn++) {
            f32x4 sv = {};
            sv = MFMA(aq0, k0[jn], sv);
            sv = MFMA(aq1, k1[jn], sv);
#pragma unroll
            for (int r = 0; r < 4; r++) rs[r] += __expf(sv[r]);
        }
    }
#pragma unroll
    for (int off = 8; off; off >>= 1)
#pragma unroll
        for (int r = 0; r < 4; r++) rs[r] += __shfl_xor(rs[r], off, 16);
    float ri[4];
#pragma unroll
    for (int r = 0; r < 4; r++) ri[r] = 1.0f / rs[r];

    // ---- pass 2 ----
    const int r0 = tid >> 3, c0 = (tid & 7) * 8;
    uint4 kreg[2], vreg[2];
#pragma unroll
    for (int rep = 0; rep < 2; rep++) {
        int r = r0 + rep * 32;
        kreg[rep] = *(const uint4*)(kb + (size_t)r * HD + c0);
        vreg[rep] = *(const uint4*)(vt + (size_t)r * T_ + c0);
    }

    f32x4 oacc[4] = {};
    float* pb0 = p_out + (size_t)bh * T_ * T_ + (size_t)(qt * 64) * T_;

    for (int kt = 0; kt < 32; kt++) {
        __syncthreads();  // A: previous iteration's LDS reads done
#pragma unroll
        for (int rep = 0; rep < 2; rep++) {
            int r = r0 + rep * 32;
            *(uint4*)&Ks[r][c0] = kreg[rep];
            *(uint4*)&Vts[r][c0] = vreg[rep];
        }
        if (kt + 1 < 32) {  // issue next tile's loads; consumed next iter
#pragma unroll
            for (int rep = 0; rep < 2; rep++) {
                int r = r0 + rep * 32;
                kreg[rep] = *(const uint4*)(kb + (size_t)((kt + 1) * 64 + r) * HD + c0);
                vreg[rep] = *(const uint4*)(vt + (size_t)r * T_ + (kt + 1) * 64 + c0);
            }
        }
        __syncthreads();  // B: tiles ready

#pragma unroll
        for (int jn = 0; jn < 4; jn++) {
            f32x4 sv = {};
            bf16x8 b0 = *(const bf16x8*)&Ks[jn * 16 + l16][quad * 8];
            bf16x8 b1 = *(const bf16x8*)&Ks[jn * 16 + l16][32 + quad * 8];
            sv = MFMA(aq0, b0, sv);
            sv = MFMA(aq1, b1, sv);
#pragma unroll
            for (int r = 0; r < 4; r++) {
                float e = __expf(sv[r]) * ri[r];
                int row = wave * 16 + quad * 4 + r;
                PsB[row][jn * 16 + l16] = (bf16)e;
                pb0[(size_t)row * T_ + kt * 64 + jn * 16 + l16] = e;
            }
        }
        // PsB is wave-local (wave writes+reads its own 16 rows): no barrier
        bf16x8 a0 = *(const bf16x8*)&PsB[wave * 16 + l16][quad * 8];
        bf16x8 a1 = *(const bf16x8*)&PsB[wave * 16 + l16][32 + quad * 8];
#pragma unroll
        for (int jb = 0; jb < 4; jb++) {
            bf16x8 b0 = *(const bf16x8*)&Vts[jb * 16 + l16][quad * 8];
            bf16x8 b1 = *(const bf16x8*)&Vts[jb * 16 + l16][32 + quad * 8];
            oacc[jb] = MFMA(a0, b0, oacc[jb]);
            oacc[jb] = MFMA(a1, b1, oacc[jb]);
        }
    }

    // O (already normalized) overwrites this block's own q tile
#pragma unroll
    for (int jb = 0; jb < 4; jb++)
#pragma unroll
        for (int r = 0; r < 4; r++)
            qb[(size_t)(wave * 16 + quad * 4 + r) * HD + jb * 16 + l16] =
                (bf16)oacc[jb][r];
}

// ---------------------------------------------------------------------------
// Kernel C: out = attn @ W_out^T + b_out (fp32 out). M=4096, N=1024, K=1024.
// A (bf16) gathered from head layout [bh][t][d] (= q section of ws).
// ---------------------------------------------------------------------------
__global__ __launch_bounds__(256) void out_gemm(const bf16* __restrict__ attn,
                                                const float* __restrict__ Wout,
                                                const float* __restrict__ bout,
                                                float* __restrict__ out) {
    __shared__ bf16 As[64][40];
    __shared__ bf16 Bs[64][40];
    const int tid = threadIdx.x;
    const int mbase = blockIdx.y * 64;
    const int nbase = blockIdx.x * 64;
    const int wave = tid >> 6, lane = tid & 63;
    const int quad = lane >> 4, l16 = lane & 15;
    const int wm = (wave >> 1) * 32, wn = (wave & 1) * 32;

    f32x4 acc[2][2] = {};
    const int lrow = tid >> 2, lcol = (tid & 3) * 8;
    const int arow = mbase + lrow;
    const int tok_t = arow >> 1, tok_b = arow & 1;
    const float* gb = Wout + (size_t)(nbase + lrow) * E_ + lcol;

    for (int kk = 0; kk < E_; kk += 32) {
        int kc = kk + lcol;
        int h = kc >> 6, d = kc & 63;
        *(uint4*)&As[lrow][lcol] = *(const uint4*)(attn +
            (size_t)(tok_b * H_ + h) * T_ * HD + (size_t)tok_t * HD + d);
        *(bf16x8*)&Bs[lrow][lcol] = cvt8(gb + kk);
        __syncthreads();
        bf16x8 a0 = *(const bf16x8*)&As[wm + l16][quad * 8];
        bf16x8 a1 = *(const bf16x8*)&As[wm + 16 + l16][quad * 8];
        bf16x8 b0 = *(const bf16x8*)&Bs[wn + l16][quad * 8];
        bf16x8 b1 = *(const bf16x8*)&Bs[wn + 16 + l16][quad * 8];
        acc[0][0] = MFMA(a0, b0, acc[0][0]);
        acc[0][1] = MFMA(a0, b1, acc[0][1]);
        acc[1][0] = MFMA(a1, b0, acc[1][0]);
        acc[1][1] = MFMA(a1, b1, acc[1][1]);
        __syncthreads();
    }
    for (int i = 0; i < 2; i++)
        for (int j = 0; j < 2; j++)
            for (int r = 0; r < 4; r++) {
                int grow = mbase + wm + i * 16 + quad * 4 + r;
                int gcol = nbase + wn + j * 16 + l16;
                out[(size_t)grow * E_ + gcol] = acc[i][j][r] + bout[gcol];
            }
}

extern "C" void kernel_launch(void* const* d_in, const int* in_sizes, int n_in,
                              void* d_out, int out_size, void* d_ws, size_t ws_size,
                              hipStream_t stream) {
    const float* g = (const float*)d_in[0];
    const float* Win = (const float*)d_in[1];
    const float* bin = (const float*)d_in[2];
    const float* Wout = (const float*)d_in[3];
    const float* bout = (const float*)d_in[4];

    float* out = (float*)d_out;               // 4,194,304 fp32
    float* p = out + (size_t)M_ * E_;         // 134,217,728 fp32
    bf16* qkv_ws = (bf16*)d_ws;               // 3 * SEC bf16 = 24 MB

    qkv_gemm<<<dim3(24, 32), 256, 0, stream>>>(g, Win, bin, qkv_ws);
    attn_kernel<<<dim3(32, 32), 256, 0, stream>>>(qkv_ws, p);
    out_gemm<<<dim3(16, 64), 256, 0, stream>>>(qkv_ws, Wout, bout, out);
}